// Round 2
// baseline (5843.758 us; speedup 1.0000x reference)
//
#include <hip/hip_runtime.h>
#include <hip/hip_bf16.h>

// ---------------------------------------------------------------------------
// BasicBlock (EfficientViT-style): dw3x3+res -> MLP -> cascade window attn ->
// dw3x3+res -> MLP.  B=64, C=512, H=W=28, WS=7, NH=8, KD=16, D=64.
// Input dtype (fp32 vs bf16) detected at runtime from bit patterns; internal
// compute fp32; output stored in the matching dtype.
// ---------------------------------------------------------------------------

#define NE (64 * 512 * 784)          // elements of one [64,512,28,28] tensor
#define HW 784
#define CHW (512 * 784)
#define NWIN 1024                    // 64 * 4 * 4 windows
#define NTOT (NWIN * 49)             // 50176

typedef __hip_bfloat16 bf16;

// Detect whether `probe` (first input tensor, values ~N(0,1)) is packed bf16
// or fp32. Looks at low 16 bits of first 64 words: in a bf16 buffer these are
// valid bf16 values (exponent field in a sane range); in fp32 they are random
// mantissa bits (~16% hit rate). Uniform across threads -> scalar loads.
__device__ __forceinline__ bool is_bf16_buf(const void* probe) {
    const unsigned* w = (const unsigned*)probe;
    int hits = 0;
#pragma unroll
    for (int i = 0; i < 64; i++) {
        unsigned lo = w[i] & 0xFFFFu;
        unsigned e = (lo >> 7) & 0xFFu;
        hits += ((e >= 100u && e <= 140u) || lo == 0u) ? 1 : 0;
    }
    return hits >= 32;
}

// Load from an INPUT tensor (dtype per detected flag).
template <bool ISBF>
__device__ __forceinline__ float ldin(const void* p, size_t i) {
    if constexpr (ISBF) return __bfloat162float(((const bf16*)p)[i]);
    else return ((const float*)p)[i];
}

// Load from a source that may be input (0), float ws (1), or bf16 ws (2).
template <bool ISBF, int KIND>
__device__ __forceinline__ float ldsrc(const void* p, size_t i) {
    if constexpr (KIND == 1) return ((const float*)p)[i];
    else if constexpr (KIND == 2) return __bfloat162float(((const bf16*)p)[i]);
    else return ldin<ISBF>(p, i);
}

// Store: 0 = float ws, 1 = output (dtype per flag), 2 = bf16 ws.
template <bool ISBF, int KIND>
__device__ __forceinline__ void stdst(void* p, size_t i, float v) {
    if constexpr (KIND == 0) ((float*)p)[i] = v;
    else if constexpr (KIND == 2) ((bf16*)p)[i] = __float2bfloat16(v);
    else {
        if constexpr (ISBF) ((bf16*)p)[i] = __float2bfloat16(v);
        else ((float*)p)[i] = v;
    }
}

__device__ __forceinline__ float hswish(float v) {
    float t = v + 3.0f;
    t = fminf(fmaxf(t, 0.0f), 6.0f);
    return v * t * (1.0f / 6.0f);
}

// ---------------------------------------------------------------------------
// Depthwise 3x3 (SAME) + residual:  out = in + conv(in, w, b)
// ---------------------------------------------------------------------------
template <bool ISBF, int INKIND>
__device__ void dw3res_body(const void* x, const void* w, const void* b,
                            float* __restrict__ out) {
    int idx = blockIdx.x * 256 + threadIdx.x;
    if (idx >= NE) return;
    int s = idx % 28;
    int r = (idx / 28) % 28;
    int c = (idx / HW) % 512;
    size_t plane = (size_t)(idx / HW) * HW;

    float wv[9];
#pragma unroll
    for (int t = 0; t < 9; t++) wv[t] = ldin<ISBF>(w, c * 9 + t);
    float acc = ldin<ISBF>(b, c);

#pragma unroll
    for (int dy = -1; dy <= 1; dy++) {
        int rr = r + dy;
        if (rr < 0 || rr >= 28) continue;
#pragma unroll
        for (int dx = -1; dx <= 1; dx++) {
            int ss = s + dx;
            if (ss < 0 || ss >= 28) continue;
            acc += ldsrc<ISBF, INKIND>(x, plane + rr * 28 + ss) * wv[(dy + 1) * 3 + (dx + 1)];
        }
    }
    out[idx] = ldsrc<ISBF, INKIND>(x, idx) + acc;
}

template <int INKIND>
__global__ __launch_bounds__(256) void k_dw3res(const void* x, const void* w, const void* b,
                                                float* out, const void* probe) {
    if (is_bf16_buf(probe)) dw3res_body<true, INKIND>(x, w, b, out);
    else dw3res_body<false, INKIND>(x, w, b, out);
}

// ---------------------------------------------------------------------------
// Pointwise (1x1) GEMM:  out[b,o,n] = act( sum_c in[b,c,n] * w[o,c] + bias[o] ) (+res)
// Tile: 64 (o) x 64 (n), 256 threads, 4x4 per thread, K-chunks of 16.
// out_mode 0: plain [b, COUT, HWdim] (+res, same layout)
// out_mode 1: window-merge: b==0, HWdim==NTOT, n = win*49 + p; write NCHW + res.
// ---------------------------------------------------------------------------
template <bool ISBF, int INKIND, int OUTKIND>
__device__ void pw_body(const void* in, const void* wgt, const void* bias,
                        const float* __restrict__ res, void* out,
                        int CIN, int HWdim, int act, int out_mode) {
    __shared__ __align__(16) float sA[16][68];
    __shared__ __align__(16) float sB[16][68];

    const int b = blockIdx.z;
    const int o0 = blockIdx.y * 64;
    const int hw0 = blockIdx.x * 64;
    const int COUT = gridDim.y * 64;
    const int tid = threadIdx.x;
    const int tx = tid & 15, ty = tid >> 4;

    const size_t inoff = (size_t)b * CIN * HWdim;
    float acc[4][4] = {};

    for (int k0 = 0; k0 < CIN; k0 += 16) {
#pragma unroll
        for (int r = 0; r < 4; r++) {
            int e = r * 256 + tid;
            int kk = e & 15, oo = e >> 4;
            sA[kk][oo] = ldin<ISBF>(wgt, (size_t)(o0 + oo) * CIN + k0 + kk);
            int nn = e & 63, kk2 = e >> 6;
            int hw = hw0 + nn;
            sB[kk2][nn] = (hw < HWdim) ? ldsrc<ISBF, INKIND>(in, inoff + (size_t)(k0 + kk2) * HWdim + hw)
                                       : 0.0f;
        }
        __syncthreads();
#pragma unroll
        for (int kk = 0; kk < 16; kk++) {
            const float4 av = *(const float4*)(&sA[kk][ty * 4]);
            const float4 bv = *(const float4*)(&sB[kk][tx * 4]);
            float a4[4] = {av.x, av.y, av.z, av.w};
            float b4[4] = {bv.x, bv.y, bv.z, bv.w};
#pragma unroll
            for (int i = 0; i < 4; i++)
#pragma unroll
                for (int j = 0; j < 4; j++) acc[i][j] = fmaf(a4[i], b4[j], acc[i][j]);
        }
        __syncthreads();
    }

#pragma unroll
    for (int i = 0; i < 4; i++) {
        int o = o0 + ty * 4 + i;
        float bv = ldin<ISBF>(bias, o);
#pragma unroll
        for (int j = 0; j < 4; j++) {
            int hw = hw0 + tx * 4 + j;
            if (hw >= HWdim) continue;
            float v = acc[i][j] + bv;
            if (act) v = hswish(v);
            if (out_mode == 0) {
                size_t oi = ((size_t)b * COUT + o) * HWdim + hw;
                if (res) v += res[oi];
                stdst<ISBF, OUTKIND>(out, oi, v);
            } else {
                int w = hw / 49, n = hw % 49;
                int wb = w >> 4, wh = (w >> 2) & 3, ww = w & 3;
                int r2 = n / 7, s2 = n % 7;
                size_t oi = ((size_t)wb * 512 + o) * HW + (size_t)(wh * 7 + r2) * 28 + ww * 7 + s2;
                stdst<ISBF, OUTKIND>(out, oi, v + res[oi]);
            }
        }
    }
}

template <int INKIND, int OUTKIND>
__global__ __launch_bounds__(256) void k_pw(const void* in, const void* wgt, const void* bias,
                                            const float* res, void* out,
                                            int CIN, int HWdim, int act, int out_mode,
                                            const void* probe) {
    if (is_bf16_buf(probe)) pw_body<true, INKIND, OUTKIND>(in, wgt, bias, res, out, CIN, HWdim, act, out_mode);
    else pw_body<false, INKIND, OUTKIND>(in, wgt, bias, res, out, CIN, HWdim, act, out_mode);
}

// ---------------------------------------------------------------------------
// Cascade window attention. One block (256 thr) per 7x7 window.
// Reads y2 (fp32 NCHW). Writes ywin[c][win*49 + n] = hswish(concat_outs), fp32.
// ---------------------------------------------------------------------------
template <bool ISBF>
__device__ void attn_body(const float* __restrict__ y2,
                          const void* qkv_w, const void* qkv_b,
                          const void* dwq_w7, const void* dwq_b7,
                          const void* dwq_w5, const void* dwq_b5,
                          const void* dwq_w3, const void* dwq_b3,
                          const void* attn_bias, float* __restrict__ ywin) {
    __shared__ float sp[64][50];
    __shared__ float yq[96][50];
    __shared__ float qc[16][50];
    __shared__ float att[49][50];

    const int w = blockIdx.x;
    const int wb = w >> 4, wh = (w >> 2) & 3, ww = w & 3;
    const int tid = threadIdx.x;
    const size_t basep = (size_t)wb * CHW + (size_t)(wh * 7) * 28 + ww * 7;

    for (int i = 0; i < 8; i++) {
        // 1. cascade input accumulate
        for (int e = tid; e < 64 * 49; e += 256) {
            int d = e / 49, n = e % 49;
            int r = n / 7, s = n % 7;
            float v = y2[basep + (size_t)(i * 64 + d) * HW + r * 28 + s];
            sp[d][n] = (i == 0) ? v : sp[d][n] + v;
        }
        __syncthreads();

        // 2. qkv pw: [96,64] @ sp[64,49]
        const size_t qwo = (size_t)i * 96 * 64;
        for (int e = tid; e < 96 * 49; e += 256) {
            int o = e / 49, n = e % 49;
            float acc = ldin<ISBF>(qkv_b, i * 96 + o);
#pragma unroll 16
            for (int c = 0; c < 64; c++) acc += ldin<ISBF>(qkv_w, qwo + o * 64 + c) * sp[c][n];
            yq[o][n] = acc;
        }
        __syncthreads();

        // 3. depthwise conv on q (rows 0..15 of yq)
        const int ks = (i == 0) ? 7 : (i == 1) ? 5 : 3;
        const int pad = ks >> 1;
        const void* cw;
        const void* cb;
        size_t cwo = 0, cbo = 0;
        if (i == 0) { cw = dwq_w7; cb = dwq_b7; }
        else if (i == 1) { cw = dwq_w5; cb = dwq_b5; }
        else { cw = dwq_w3; cb = dwq_b3; cwo = (size_t)(i - 2) * 16 * 9; cbo = (size_t)(i - 2) * 16; }
        for (int e = tid; e < 16 * 49; e += 256) {
            int d = e / 49, n = e % 49;
            int r = n / 7, s = n % 7;
            float acc = ldin<ISBF>(cb, cbo + d);
            for (int dy = 0; dy < ks; dy++) {
                int rr = r + dy - pad;
                if (rr < 0 || rr >= 7) continue;
                for (int dx = 0; dx < ks; dx++) {
                    int ss = s + dx - pad;
                    if (ss < 0 || ss >= 7) continue;
                    acc += ldin<ISBF>(cw, cwo + d * ks * ks + dy * ks + dx) * yq[d][rr * 7 + ss];
                }
            }
            qc[d][n] = acc;
        }
        __syncthreads();

        // 4. scores
        for (int e = tid; e < 49 * 49; e += 256) {
            int n = e / 49, m = e % 49;
            float acc = 0.0f;
#pragma unroll
            for (int c = 0; c < 16; c++) acc += qc[c][n] * yq[16 + c][m];
            int r1 = n / 7, c1 = n % 7, r2 = m / 7, c2 = m % 7;
            int off = abs(r1 - r2) * 7 + abs(c1 - c2);
            att[n][m] = acc * 0.25f + ldin<ISBF>(attn_bias, i * 49 + off);
        }
        __syncthreads();

        // 5. softmax over m
        if (tid < 49) {
            float mx = -1e30f;
            for (int m = 0; m < 49; m++) mx = fmaxf(mx, att[tid][m]);
            float sm = 0.0f;
            for (int m = 0; m < 49; m++) {
                float e2 = __expf(att[tid][m] - mx);
                att[tid][m] = e2;
                sm += e2;
            }
            float inv = 1.0f / sm;
            for (int m = 0; m < 49; m++) att[tid][m] *= inv;
        }
        __syncthreads();

        // 6. out = v @ att^T; keep in sp for cascade; write hswish'd to ywin
        for (int e = tid; e < 64 * 49; e += 256) {
            int d = e / 49, n = e % 49;
            float acc = 0.0f;
#pragma unroll 7
            for (int m = 0; m < 49; m++) acc += yq[32 + d][m] * att[n][m];
            sp[d][n] = acc;
            ywin[(size_t)(i * 64 + d) * NTOT + w * 49 + n] = hswish(acc);
        }
        __syncthreads();
    }
}

__global__ __launch_bounds__(256) void k_attn(const float* y2,
                                              const void* qkv_w, const void* qkv_b,
                                              const void* dwq_w7, const void* dwq_b7,
                                              const void* dwq_w5, const void* dwq_b5,
                                              const void* dwq_w3, const void* dwq_b3,
                                              const void* attn_bias, float* ywin,
                                              const void* probe) {
    if (is_bf16_buf(probe)) attn_body<true>(y2, qkv_w, qkv_b, dwq_w7, dwq_b7, dwq_w5, dwq_b5, dwq_w3, dwq_b3, attn_bias, ywin);
    else attn_body<false>(y2, qkv_w, qkv_b, dwq_w7, dwq_b7, dwq_w5, dwq_b5, dwq_w3, dwq_b3, attn_bias, ywin);
}

// ---------------------------------------------------------------------------

extern "C" void kernel_launch(void* const* d_in, const int* in_sizes, int n_in,
                              void* d_out, int out_size, void* d_ws, size_t ws_size,
                              hipStream_t stream) {
    const void* x       = d_in[0];
    const void* dw0_w   = d_in[1];
    const void* dw0_b   = d_in[2];
    const void* ffn0_w1 = d_in[3];
    const void* ffn0_b1 = d_in[4];
    const void* ffn0_w2 = d_in[5];
    const void* ffn0_b2 = d_in[6];
    const void* qkv_w   = d_in[7];
    const void* qkv_b   = d_in[8];
    const void* dwq_w7  = d_in[9];
    const void* dwq_b7  = d_in[10];
    const void* dwq_w5  = d_in[11];
    const void* dwq_b5  = d_in[12];
    const void* dwq_w3  = d_in[13];
    const void* dwq_b3  = d_in[14];
    const void* attn_b  = d_in[15];
    const void* proj_w  = d_in[16];
    const void* proj_b  = d_in[17];
    const void* dw1_w   = d_in[18];
    const void* dw1_b   = d_in[19];
    const void* ffn1_w1 = d_in[20];
    const void* ffn1_b1 = d_in[21];
    const void* ffn1_w2 = d_in[22];
    const void* ffn1_b2 = d_in[23];

    if (ws_size < (size_t)3 * NE * sizeof(float)) return;  // insufficient scratch

    float* wsf = (float*)d_ws;
    float* y1   = wsf;                      // [0, NE)
    bf16*  hid  = (bf16*)(wsf + NE);        // [NE, 2NE): 2*NE bf16 elements
    float* y2   = wsf + 2 * (size_t)NE;     // [2NE, 3NE)
    float* ywin = y1;                       // reuse after y1 consumed
    float* x3   = wsf + NE;                 // reuse hid region
    float* x4   = y2;                       // reuse y2 region
    bf16*  hid2 = hid;                      // reuse hid region

    dim3 blk(256);
    int nblk = (NE + 255) / 256;

    // 1. y1 = x + dw0(x)
    k_dw3res<0><<<nblk, blk, 0, stream>>>(x, dw0_w, dw0_b, y1, x);
    // 2. hid = hswish(pw(y1, w1, b1))
    k_pw<1, 2><<<dim3(13, 16, 64), blk, 0, stream>>>(y1, ffn0_w1, ffn0_b1, nullptr, hid, 512, HW, 1, 0, x);
    // 3. y2 = y1 + pw(hid, w2, b2)
    k_pw<2, 0><<<dim3(13, 8, 64), blk, 0, stream>>>(hid, ffn0_w2, ffn0_b2, y1, y2, 1024, HW, 0, 0, x);
    // 4. cascade attention -> ywin [512, 50176] (hswish applied)
    k_attn<<<NWIN, blk, 0, stream>>>(y2, qkv_w, qkv_b, dwq_w7, dwq_b7, dwq_w5, dwq_b5,
                                     dwq_w3, dwq_b3, attn_b, ywin, x);
    // 5. x3 = y2 + merge(pw(ywin, proj_w, proj_b))
    k_pw<1, 0><<<dim3(784, 8, 1), blk, 0, stream>>>(ywin, proj_w, proj_b, y2, x3, 512, NTOT, 0, 1, x);
    // 6. x4 = x3 + dw1(x3)
    k_dw3res<1><<<nblk, blk, 0, stream>>>(x3, dw1_w, dw1_b, x4, x);
    // 7. hid2 = hswish(pw(x4, w1, b1))
    k_pw<1, 2><<<dim3(13, 16, 64), blk, 0, stream>>>(x4, ffn1_w1, ffn1_b1, nullptr, hid2, 512, HW, 1, 0, x);
    // 8. out = x4 + pw(hid2, w2, b2)
    k_pw<2, 1><<<dim3(13, 8, 64), blk, 0, stream>>>(hid2, ffn1_w2, ffn1_b2, x4, d_out, 1024, HW, 0, 0, x);
}

// Round 4
// 1934.793 us; speedup vs baseline: 3.0204x; 3.0204x over previous
//
#include <hip/hip_runtime.h>
#include <hip/hip_bf16.h>

// ---------------------------------------------------------------------------
// BasicBlock (EfficientViT-style) on MI355X. Input dtype (fp32 vs bf16) is
// runtime-detected; all weights are pre-converted into a bf16 arena in ws so
// the compute kernels are dtype-free. GEMMs: bf16 MFMA, fp32 accum.
//
// Layouts:
//   CT = [C][N]  n-contiguous (N = 50176 = 64*784) fp32, residuals/attn in.
//   NK = [N][K]  k-contiguous bf16, MFMA GEMM operands (ds_read_b128 frags).
// ---------------------------------------------------------------------------

#define NPOS 50176                  // 64 * 784
#define NEL ((size_t)512 * NPOS)

typedef __hip_bfloat16 hbf;
typedef __attribute__((ext_vector_type(8))) short short8;   // 8 bf16
typedef __attribute__((ext_vector_type(4))) float f32x4;

__device__ __forceinline__ float hswish(float v) {
    float t = fminf(fmaxf(v + 3.0f, 0.0f), 6.0f);
    return v * t * (1.0f / 6.0f);
}
__device__ __forceinline__ float b2f(hbf x) { return __bfloat162float(x); }
__device__ __forceinline__ hbf f2b(float x) { return __float2bfloat16(x); }

// Probe x's dtype: low 16 bits of fp32 words are random mantissa bits (~16%
// "sane bf16 exponent" rate); in a packed-bf16 buffer they are real bf16
// values (~100%). 64 words, threshold 32 -> error prob < 1e-10.
__device__ __forceinline__ bool is_bf16_buf(const void* probe) {
    const unsigned* w = (const unsigned*)probe;
    int hits = 0;
#pragma unroll
    for (int i = 0; i < 64; i++) {
        unsigned lo = w[i] & 0xFFFFu;
        unsigned e = (lo >> 7) & 0xFFu;
        hits += ((e >= 100u && e <= 140u) || lo == 0u) ? 1 : 0;
    }
    return hits >= 32;
}

// ---------------------------------------------------------------------------
// Weight arena (bf16) — compile-time element offsets.
// ---------------------------------------------------------------------------
#define OFF_W01  0          // ffn0_w1 [1024][512]
#define OFF_W02  524288     // ffn0_w2 [512][1024]
#define OFF_W11  1048576    // ffn1_w1 [1024][512]
#define OFF_W12  1572864    // ffn1_w2 [512][1024]
#define OFF_PW   2097152    // proj_w  [512][512]
#define OFF_QKVW 2359296    // qkv_w   [8][96][64]
#define OFF_QKVB 2408448    // qkv_b   [8][96]
#define OFF_W7   2409216
#define OFF_B7   2410000
#define OFF_W5   2410016
#define OFF_B5   2410416
#define OFF_W3   2410432    // [6][16][9]
#define OFF_B3   2411296    // [6][16]
#define OFF_AB   2411392    // [8][49]
#define OFF_D0W  2411784    // dw0_w [512][9]
#define OFF_D0B  2416392
#define OFF_D1W  2416904
#define OFF_D1B  2421512
#define OFF_B01  2422024    // ffn0_b1 [1024]
#define OFF_B02  2423048
#define OFF_B11  2423560
#define OFF_B12  2424584
#define OFF_PB   2425096
#define ARENA_TOT 2425608

struct CvtArgs { const void* src; int off; int count; };
struct CvtTable { CvtArgs t[23]; };

__global__ __launch_bounds__(256) void k_convert(CvtTable tab, hbf* __restrict__ arena,
                                                 const void* __restrict__ probe) {
    bool isbf = is_bf16_buf(probe);
    CvtArgs a = tab.t[blockIdx.y];
    int i = blockIdx.x * 256 + threadIdx.x;
    if (i >= a.count) return;
    float v = isbf ? b2f(((const hbf*)a.src)[i]) : ((const float*)a.src)[i];
    arena[a.off + i] = f2b(v);
}

// ---------------------------------------------------------------------------
// MFMA GEMM: D[m][n] = A[m][:] . B[n][:]  (both k-contiguous rows, bf16)
// 128x128 tile, BK=32, 4 waves, 4x4 frags of mfma_f32_16x16x32_bf16.
// EPI: 0=HID  bf16 NK [m_sp][1024] = hswish(acc + bias[n])
//      1=Y2   f32 CT [m_och][NPOS] = acc + bias[m] + bf16resNK[n][512]
//      2=PROJ f32 CT [m_och][perm(n)] = acc + bias[m] + f32resCT[same]
//      3=OUT  NCHW (bf16 or f32 per probe) = acc + bias[m] + f32resCT
// ---------------------------------------------------------------------------
template <int EPI, int K>
__global__ __launch_bounds__(256) void k_gemm(const hbf* __restrict__ A,
                                              const hbf* __restrict__ B,
                                              const hbf* __restrict__ bias,
                                              const void* __restrict__ res,
                                              void* __restrict__ out,
                                              const void* __restrict__ probe) {
    __shared__ short sA[128 * 40];   // 32 k padded to 40 shorts (80 B rows)
    __shared__ short sB[128 * 40];

    const int tid = threadIdx.x;
    const int wave = tid >> 6, lane = tid & 63;
    const int col = lane & 15, quad = lane >> 4;
    const int m0 = blockIdx.x * 128, n0 = blockIdx.y * 128;
    const int wm = (wave & 1) * 64, wn = (wave >> 1) * 64;

    const int r0 = tid >> 2, c0 = tid & 3;
    const int r1 = 64 + (tid >> 2), c1 = tid & 3;

    f32x4 acc[4][4];
#pragma unroll
    for (int i = 0; i < 4; i++)
#pragma unroll
        for (int j = 0; j < 4; j++) acc[i][j] = (f32x4){0.f, 0.f, 0.f, 0.f};

    short8 pA0 = *(const short8*)(A + (size_t)(m0 + r0) * K + c0 * 8);
    short8 pA1 = *(const short8*)(A + (size_t)(m0 + r1) * K + c1 * 8);
    short8 pB0 = *(const short8*)(B + (size_t)(n0 + r0) * K + c0 * 8);
    short8 pB1 = *(const short8*)(B + (size_t)(n0 + r1) * K + c1 * 8);

    for (int k0 = 0; k0 < K; k0 += 32) {
        __syncthreads();
        *(short8*)(sA + r0 * 40 + c0 * 8) = pA0;
        *(short8*)(sA + r1 * 40 + c1 * 8) = pA1;
        *(short8*)(sB + r0 * 40 + c0 * 8) = pB0;
        *(short8*)(sB + r1 * 40 + c1 * 8) = pB1;
        if (k0 + 32 < K) {
            pA0 = *(const short8*)(A + (size_t)(m0 + r0) * K + k0 + 32 + c0 * 8);
            pA1 = *(const short8*)(A + (size_t)(m0 + r1) * K + k0 + 32 + c1 * 8);
            pB0 = *(const short8*)(B + (size_t)(n0 + r0) * K + k0 + 32 + c0 * 8);
            pB1 = *(const short8*)(B + (size_t)(n0 + r1) * K + k0 + 32 + c1 * 8);
        }
        __syncthreads();

        short8 af[4], bfr[4];
#pragma unroll
        for (int i = 0; i < 4; i++)
            af[i] = *(const short8*)(sA + (wm + i * 16 + col) * 40 + quad * 8);
#pragma unroll
        for (int j = 0; j < 4; j++)
            bfr[j] = *(const short8*)(sB + (wn + j * 16 + col) * 40 + quad * 8);
#pragma unroll
        for (int i = 0; i < 4; i++)
#pragma unroll
            for (int j = 0; j < 4; j++)
                acc[i][j] = __builtin_amdgcn_mfma_f32_16x16x32_bf16(af[i], bfr[j], acc[i][j], 0, 0, 0);
    }

    bool outbf = false;
    if constexpr (EPI == 3) outbf = is_bf16_buf(probe);

#pragma unroll
    for (int i = 0; i < 4; i++) {
#pragma unroll
        for (int j = 0; j < 4; j++) {
#pragma unroll
            for (int r = 0; r < 4; r++) {
                int mi = m0 + wm + i * 16 + quad * 4 + r;
                int nj = n0 + wn + j * 16 + col;
                float v = acc[i][j][r];
                if constexpr (EPI == 0) {
                    v = hswish(v + b2f(bias[nj]));
                    ((hbf*)out)[(size_t)mi * 1024 + nj] = f2b(v);
                } else if constexpr (EPI == 1) {
                    v += b2f(bias[mi]) + b2f(((const hbf*)res)[(size_t)nj * 512 + mi]);
                    ((float*)out)[(size_t)mi * NPOS + nj] = v;
                } else if constexpr (EPI == 2) {
                    int w = nj / 49, p = nj % 49;
                    int nct = (w >> 4) * 784 + (((w >> 2) & 3) * 7 + p / 7) * 28 + (w & 3) * 7 + p % 7;
                    size_t oi = (size_t)mi * NPOS + nct;
                    v += b2f(bias[mi]) + ((const float*)res)[oi];
                    ((float*)out)[oi] = v;
                } else {
                    int b = nj / 784, hw = nj % 784;
                    v += b2f(bias[mi]) + ((const float*)res)[(size_t)mi * NPOS + nj];
                    size_t oi = ((size_t)b * 512 + mi) * 784 + hw;
                    if (outbf) ((hbf*)out)[oi] = f2b(v);
                    else ((float*)out)[oi] = v;
                }
            }
        }
    }
}

// ---------------------------------------------------------------------------
// Depthwise 3x3 + residual, LDS-transposed to NK bf16 output.
// MODE 0: in = x NCHW (dtype per probe)  -> outNK
// MODE 1: in = x3f CT f32 -> outNK + outCT f32
// ---------------------------------------------------------------------------
template <int MODE, bool ISBF>
__device__ void dw_body(float (*tile)[65], const void* __restrict__ in,
                        const hbf* __restrict__ w, const hbf* __restrict__ bias,
                        hbf* __restrict__ outNK, float* __restrict__ outCT) {
    const int tid = threadIdx.x;
    const int tx = tid & 63, tg = tid >> 6;
    const int n0 = blockIdx.x * 64, c0 = blockIdx.y * 64;

    const int n = n0 + tx;
    const int b = n / 784, hw = n % 784;
    const int r = hw / 28, s = hw % 28;

    for (int cc = tg; cc < 64; cc += 4) {
        const int c = c0 + cc;
        float wv[9];
#pragma unroll
        for (int t = 0; t < 9; t++) wv[t] = b2f(w[c * 9 + t]);
        float acc = b2f(bias[c]);
        float center = 0.0f;
#pragma unroll
        for (int dy = -1; dy <= 1; dy++) {
            int rr = r + dy;
            if (rr < 0 || rr >= 28) continue;
#pragma unroll
            for (int dx = -1; dx <= 1; dx++) {
                int ss = s + dx;
                if (ss < 0 || ss >= 28) continue;
                float v;
                if constexpr (MODE == 0) {
                    size_t ix = ((size_t)b * 512 + c) * 784 + rr * 28 + ss;
                    v = ISBF ? b2f(((const hbf*)in)[ix]) : ((const float*)in)[ix];
                } else {
                    v = ((const float*)in)[(size_t)c * NPOS + (size_t)b * 784 + rr * 28 + ss];
                }
                acc += v * wv[(dy + 1) * 3 + (dx + 1)];
                if (dy == 0 && dx == 0) center = v;
            }
        }
        float val = center + acc;
        tile[cc][tx] = val;
        if constexpr (MODE == 1) outCT[(size_t)c * NPOS + n] = val;
    }
    __syncthreads();
    for (int q = tg; q < 64; q += 4)
        outNK[(size_t)(n0 + q) * 512 + c0 + tx] = f2b(tile[tx][q]);
}

template <int MODE>
__global__ __launch_bounds__(256) void k_dw(const void* in, const hbf* w, const hbf* b,
                                            hbf* outNK, float* outCT, const void* probe) {
    __shared__ float tile[64][65];
    if constexpr (MODE == 1) {
        dw_body<1, false>(tile, in, w, b, outNK, outCT);
    } else {
        if (is_bf16_buf(probe)) dw_body<0, true>(tile, in, w, b, outNK, outCT);
        else dw_body<0, false>(tile, in, w, b, outNK, outCT);
    }
}

// ---------------------------------------------------------------------------
// Cascade window attention. One block per 7x7 window; 8 heads sequential.
// In: y2f CT f32. Out: ywin NK bf16 [w*49+p][512] = hswish(concat heads).
// ---------------------------------------------------------------------------
__global__ __launch_bounds__(256) void k_attn(const float* __restrict__ y2,
                                              const hbf* __restrict__ arena,
                                              hbf* __restrict__ ywin) {
    __shared__ float sp[64][51];
    __shared__ float yq[96][51];
    __shared__ float qc[16][51];
    __shared__ float att[49][51];

    const hbf* qkv_w = arena + OFF_QKVW;
    const hbf* qkv_b = arena + OFF_QKVB;
    const hbf* ab    = arena + OFF_AB;

    const int w = blockIdx.x;
    const int wb = w >> 4, wh = (w >> 2) & 3, ww = w & 3;
    const int tid = threadIdx.x;
    const size_t base = (size_t)wb * 784 + (size_t)(wh * 7) * 28 + ww * 7;

    for (int i = 0; i < 8; i++) {
        for (int e = tid; e < 64 * 49; e += 256) {
            int d = e / 49, n = e % 49;
            float v = y2[(size_t)(i * 64 + d) * NPOS + base + (n / 7) * 28 + (n % 7)];
            sp[d][n] = (i == 0) ? v : sp[d][n] + v;
        }
        __syncthreads();

        for (int e = tid; e < 96 * 49; e += 256) {
            int o = e / 49, n = e % 49;
            float acc = b2f(qkv_b[i * 96 + o]);
            const hbf* wr = qkv_w + (size_t)i * 96 * 64 + o * 64;
#pragma unroll 16
            for (int c = 0; c < 64; c++) acc += b2f(wr[c]) * sp[c][n];
            yq[o][n] = acc;
        }
        __syncthreads();

        const int ks = (i == 0) ? 7 : (i == 1) ? 5 : 3;
        const int pad = ks >> 1;
        const hbf* cw; const hbf* cb;
        if (i == 0)      { cw = arena + OFF_W7; cb = arena + OFF_B7; }
        else if (i == 1) { cw = arena + OFF_W5; cb = arena + OFF_B5; }
        else             { cw = arena + OFF_W3 + (i - 2) * 144; cb = arena + OFF_B3 + (i - 2) * 16; }
        for (int e = tid; e < 16 * 49; e += 256) {
            int d = e / 49, n = e % 49;
            int r = n / 7, s = n % 7;
            float acc = b2f(cb[d]);
            for (int dy = 0; dy < ks; dy++) {
                int rr = r + dy - pad;
                if (rr < 0 || rr >= 7) continue;
                for (int dx = 0; dx < ks; dx++) {
                    int ss = s + dx - pad;
                    if (ss < 0 || ss >= 7) continue;
                    acc += b2f(cw[d * ks * ks + dy * ks + dx]) * yq[d][rr * 7 + ss];
                }
            }
            qc[d][n] = acc;
        }
        __syncthreads();

        for (int e = tid; e < 49 * 49; e += 256) {
            int n = e / 49, m = e % 49;
            float acc = 0.0f;
#pragma unroll
            for (int c = 0; c < 16; c++) acc += qc[c][n] * yq[16 + c][m];
            int off = abs(n / 7 - m / 7) * 7 + abs(n % 7 - m % 7);
            att[n][m] = acc * 0.25f + b2f(ab[i * 49 + off]);
        }
        __syncthreads();

        if (tid < 49) {
            float mx = -1e30f;
            for (int m = 0; m < 49; m++) mx = fmaxf(mx, att[tid][m]);
            float sm = 0.0f;
            for (int m = 0; m < 49; m++) {
                float e2 = __expf(att[tid][m] - mx);
                att[tid][m] = e2; sm += e2;
            }
            float inv = 1.0f / sm;
            for (int m = 0; m < 49; m++) att[tid][m] *= inv;
        }
        __syncthreads();

        for (int e = tid; e < 64 * 49; e += 256) {
            int d = e / 49, n = e % 49;
            float acc = 0.0f;
#pragma unroll 7
            for (int m = 0; m < 49; m++) acc += yq[32 + d][m] * att[n][m];
            sp[d][n] = acc;
        }
        __syncthreads();

        for (int e = tid; e < 49 * 64; e += 256) {
            int n = e >> 6, d = e & 63;
            ywin[((size_t)w * 49 + n) * 512 + i * 64 + d] = f2b(hswish(sp[d][n]));
        }
        __syncthreads();
    }
}

// ---------------------------------------------------------------------------

extern "C" void kernel_launch(void* const* d_in, const int* in_sizes, int n_in,
                              void* d_out, int out_size, void* d_ws, size_t ws_size,
                              hipStream_t stream) {
    const void* x = d_in[0];

    if (ws_size < NEL * 10 + (size_t)ARENA_TOT * 2) return;

    uint8_t* p = (uint8_t*)d_ws;
    hbf*   R0 = (hbf*)p;                          // NEL bf16
    hbf*   R1 = (hbf*)(p + NEL * 2);              // NEL*4 bytes
    float* R2 = (float*)(p + NEL * 6);            // NEL f32
    hbf*   arena = (hbf*)(p + NEL * 10);

    hbf*   y1t  = R0;
    hbf*   hid  = R1;
    float* y2f  = R2;
    hbf*   ywin = R0;
    float* x3f  = (float*)R1;
    float* x4f  = R2;
    hbf*   x4t  = R0;
    hbf*   hid2 = R1;

    CvtTable tab = {{
        { d_in[3],  OFF_W01,  524288 },  // ffn0_w1
        { d_in[5],  OFF_W02,  524288 },  // ffn0_w2
        { d_in[20], OFF_W11,  524288 },  // ffn1_w1
        { d_in[22], OFF_W12,  524288 },  // ffn1_w2
        { d_in[16], OFF_PW,   262144 },  // proj_w
        { d_in[7],  OFF_QKVW, 49152 },   // qkv_w
        { d_in[8],  OFF_QKVB, 768 },     // qkv_b
        { d_in[9],  OFF_W7,   784 },
        { d_in[10], OFF_B7,   16 },
        { d_in[11], OFF_W5,   400 },
        { d_in[12], OFF_B5,   16 },
        { d_in[13], OFF_W3,   864 },
        { d_in[14], OFF_B3,   96 },
        { d_in[15], OFF_AB,   392 },
        { d_in[1],  OFF_D0W,  4608 },
        { d_in[2],  OFF_D0B,  512 },
        { d_in[18], OFF_D1W,  4608 },
        { d_in[19], OFF_D1B,  512 },
        { d_in[4],  OFF_B01,  1024 },
        { d_in[6],  OFF_B02,  512 },
        { d_in[21], OFF_B11,  1024 },
        { d_in[23], OFF_B12,  512 },
        { d_in[17], OFF_PB,   512 },
    }};

    dim3 blk(256);

    // 0. convert all weights/biases to bf16 arena
    k_convert<<<dim3(2048, 23), blk, 0, stream>>>(tab, arena, x);
    // 1. y1t = (x + dw0(x)) NK bf16
    k_dw<0><<<dim3(NPOS / 64, 8), blk, 0, stream>>>(x, arena + OFF_D0W, arena + OFF_D0B, y1t, nullptr, x);
    // 2. hid = hswish(y1t @ ffn0_w1^T)  NK bf16 [NPOS][1024]
    k_gemm<0, 512><<<dim3(392, 8), blk, 0, stream>>>(y1t, arena + OFF_W01, arena + OFF_B01, nullptr, hid, x);
    // 3. y2f = y1 + hid @ ffn0_w2^T  CT f32
    k_gemm<1, 1024><<<dim3(4, 392), blk, 0, stream>>>(arena + OFF_W02, hid, arena + OFF_B02, y1t, y2f, x);
    // 4. attention -> ywin NK bf16 (hswish applied)
    k_attn<<<1024, blk, 0, stream>>>(y2f, arena, ywin);
    // 5. x3f = y2 + merge(ywin @ proj_w^T)  CT f32
    k_gemm<2, 512><<<dim3(4, 392), blk, 0, stream>>>(arena + OFF_PW, ywin, arena + OFF_PB, y2f, x3f, x);
    // 6. x4f CT f32 + x4t NK bf16 = x3 + dw1(x3)
    k_dw<1><<<dim3(NPOS / 64, 8), blk, 0, stream>>>(x3f, arena + OFF_D1W, arena + OFF_D1B, x4t, x4f, x);
    // 7. hid2 = hswish(x4t @ ffn1_w1^T)
    k_gemm<0, 512><<<dim3(392, 8), blk, 0, stream>>>(x4t, arena + OFF_W11, arena + OFF_B11, nullptr, hid2, x);
    // 8. out = x4 + hid2 @ ffn1_w2^T  NCHW (dtype per probe)
    k_gemm<3, 1024><<<dim3(4, 392), blk, 0, stream>>>(arena + OFF_W12, hid2, arena + OFF_B12, x4f, d_out, x);
}